// Round 27
// baseline (954.951 us; speedup 1.0000x reference)
//
#include <hip/hip_runtime.h>

#define P 16384
#define NLAYERS 5
#define NND 98304          // P*(NLAYERS+1)
#define D 64
#define S 16
#define F 80               // D+S
#define KP1 96             // K of layer-1 GEMM padded to 32
#define H 256
#define EDG 262144         // 1<<18
#define NG 64
#define NSETS 13           // 5 inner + 4 fwd + 4 bwd
#define RSP 16385          // rowstart pitch (P+1)
#define LDP 40             // LDS K-stride for 32-chunks (80B rows, <=2-way aliasing)
#define LH2 264            // H1s LDS row stride (256+8)

typedef __attribute__((ext_vector_type(8))) _Float16 f16x8;
typedef __attribute__((ext_vector_type(4))) _Float16 f16x4;
typedef __attribute__((ext_vector_type(4))) float f32x4;

// ---------------------------------------------------------------- utilities
__device__ __forceinline__ void fatomic_add(float* p, float v) {
    unsafeAtomicAdd(p, v);
}

// ---------------------------------------------------------------- init X (+fp16 mirror) + zero deg + zero PL
__global__ void k_init_x(const float* __restrict__ x0, float* __restrict__ X,
                         _Float16* __restrict__ Xh,
                         int* __restrict__ deg, float* __restrict__ PL) {
    int idx = blockIdx.x * blockDim.x + threadIdx.x;
    if (idx < NND * D) {
        int row = idx >> 6, f = idx & 63;
        float v = (f == 0) ? x0[row] : 0.0f;
        X[idx] = v;
        Xh[idx] = (_Float16)v;
        return;
    }
    int r = idx - NND * D;
    if (r < NSETS * P) { deg[r] = 0; return; }
    r -= NSETS * P;
    if (r < NG * D) PL[r] = 0.0f;
}

// ---------------------------------------------------------------- weight transpose -> fp16 + static -> fp16
__global__ void k_wconv_all(const float* __restrict__ W1, const float* __restrict__ W2,
                            const float* __restrict__ W3, const float* __restrict__ stat,
                            _Float16* __restrict__ w1, _Float16* __restrict__ w2,
                            _Float16* __restrict__ w3, _Float16* __restrict__ st16) {
    const int n1 = 4 * H * KP1, n2 = 4 * H * H, n3 = 4 * D * H;
    int idx = blockIdx.x * blockDim.x + threadIdx.x;
    if (idx >= n1 + n2 + n3) {
        int i = idx - (n1 + n2 + n3);
        if (i < NND * S) st16[i] = (_Float16)stat[i];
        return;
    }
    const float* W; _Float16* h; int K, N, Kp, i;
    if (idx < n1)              { W = W1; h = w1; K = F; N = H; Kp = KP1; i = idx; }
    else if (idx < n1 + n2)    { W = W2; h = w2; K = H; N = H; Kp = H;   i = idx - n1; }
    else                       { W = W3; h = w3; K = H; N = D; Kp = H;  i = idx - n1 - n2; }
    int set = i / (N * Kp), rem = i - set * (N * Kp);
    int n = rem / Kp, kp = rem - n * Kp;
    float v = (kp < K) ? W[(size_t)set * K * N + (size_t)kp * N + n] : 0.0f;
    h[i] = (_Float16)v;
}

// ---------------------------------------------------------------- CSR build (batched, 13 sets) — R15-proven
__device__ __forceinline__ const int* set_ptr(int t, const int* inner, const int* fwd,
                                              const int* bwd) {
    if (t < 5) return inner + (size_t)t * EDG;
    if (t < 9) return fwd + (size_t)(t - 5) * EDG;
    return bwd + (size_t)(t - 9) * EDG;
}

__global__ void k_csr_hist(const int* __restrict__ inner_dst, const int* __restrict__ fwd_dst,
                           const int* __restrict__ bwd_dst, int* __restrict__ deg,
                           int* __restrict__ rank) {
    int idx = blockIdx.x * blockDim.x + threadIdx.x;
    if (idx >= NSETS * EDG) return;
    int t = idx >> 18, e = idx & (EDG - 1);
    const int* dstp = set_ptr(t, inner_dst, fwd_dst, bwd_dst);
    rank[idx] = atomicAdd(&deg[t * P + dstp[e]], 1);
}

__global__ __launch_bounds__(1024) void k_csr_scan(const int* __restrict__ deg,
                                                   int* __restrict__ rowstart) {
    __shared__ int part[1024];
    int t = blockIdx.x;
    const int* d = deg + t * P;
    int* rs = rowstart + (size_t)t * RSP;
    int tid = threadIdx.x;
    int base = tid * 16;
    int loc[16], sum = 0;
#pragma unroll
    for (int i = 0; i < 16; ++i) { loc[i] = sum; sum += d[base + i]; }
    part[tid] = sum;
    __syncthreads();
    for (int off = 1; off < 1024; off <<= 1) {
        int v = (tid >= off) ? part[tid - off] : 0;
        __syncthreads();
        part[tid] += v;
        __syncthreads();
    }
    int pre = tid ? part[tid - 1] : 0;
#pragma unroll
    for (int i = 0; i < 16; ++i) rs[base + i] = pre + loc[i];
    if (tid == 1023) rs[P] = pre + sum;
}

__global__ void k_csr_scatter(const int* __restrict__ inner_src, const int* __restrict__ inner_dst,
                              const int* __restrict__ fwd_src, const int* __restrict__ fwd_dst,
                              const int* __restrict__ bwd_src, const int* __restrict__ bwd_dst,
                              const int* __restrict__ rowstart, const int* __restrict__ rank,
                              int* __restrict__ elist) {
    int idx = blockIdx.x * blockDim.x + threadIdx.x;
    if (idx >= NSETS * EDG) return;
    int t = idx >> 18, e = idx & (EDG - 1);
    const int* srcp = set_ptr(t, inner_src, fwd_src, bwd_src);
    const int* dstp = set_ptr(t, inner_dst, fwd_dst, bwd_dst);
    int dv = dstp[e];
    elist[(size_t)t * EDG + rowstart[(size_t)t * RSP + dv] + rank[idx]] = srcp[e];
}

// ---------------------------------------------------------------- gather conv input (wave per node, 4-row ILP, fp16 reads)
__global__ __launch_bounds__(256) void k_gather_T(const float* __restrict__ X,
                                                  const _Float16* __restrict__ Xh,
                                                  const _Float16* __restrict__ st16,
                                                  const int* __restrict__ elist,
                                                  const int* __restrict__ rowstart,
                                                  _Float16* __restrict__ Th,
                                                  int dst_gbase, int src_gbase,
                                                  const float* __restrict__ eps, int ei,
                                                  const float* __restrict__ stf) {
    int wv = threadIdx.x >> 6, l = threadIdx.x & 63;
    int v = blockIdx.x * 4 + wv;
    int beg = rowstart[v], end = rowstart[v + 1];
    float scale = 1.0f + eps[ei];
    int rg = l >> 4, c = l & 15;
    float ax0 = 0.f, ax1 = 0.f, ax2 = 0.f, ax3 = 0.f, as = 0.f;
    int i = beg;
    for (; i + 4 <= end; i += 4) {
        int s = src_gbase + elist[i + rg];
        f16x4 xv = *(const f16x4*)&Xh[(size_t)s * D + 4 * c];
        ax0 += (float)xv[0]; ax1 += (float)xv[1]; ax2 += (float)xv[2]; ax3 += (float)xv[3];
        as += (float)st16[(size_t)s * S + c];
    }
    if (i < end) {
        int rem = end - i;
        if (rg < rem) {
            int s = src_gbase + elist[i + rg];
            f16x4 xv = *(const f16x4*)&Xh[(size_t)s * D + 4 * c];
            ax0 += (float)xv[0]; ax1 += (float)xv[1]; ax2 += (float)xv[2]; ax3 += (float)xv[3];
            as += (float)st16[(size_t)s * S + c];
        }
    }
#pragma unroll
    for (int off = 16; off < 64; off <<= 1) {
        ax0 += __shfl_xor(ax0, off, 64);
        ax1 += __shfl_xor(ax1, off, 64);
        ax2 += __shfl_xor(ax2, off, 64);
        ax3 += __shfl_xor(ax3, off, 64);
        as  += __shfl_xor(as,  off, 64);
    }
    if (l < 16) {
        int g = dst_gbase + v;
        float4 sx = *(const float4*)&X[(size_t)g * D + 4 * l];
        f16x4 hv;
        hv[0] = (_Float16)(ax0 + scale * sx.x);
        hv[1] = (_Float16)(ax1 + scale * sx.y);
        hv[2] = (_Float16)(ax2 + scale * sx.z);
        hv[3] = (_Float16)(ax3 + scale * sx.w);
        *(f16x4*)&Th[(size_t)v * KP1 + 4 * l] = hv;
        Th[(size_t)v * KP1 + D + l] = (_Float16)(as + scale * stf[(size_t)g * S + l]);
        Th[(size_t)v * KP1 + F + l] = (_Float16)0.0f;   // pad cols 80..95
    }
}

// ---------------------------------------------------------------- fused conv MLP: T -> H1(LDS) -> H2(regs) -> X
// 64-row tile, 8 waves, 2 blocks/CU (70 KB LDS). H2 kept in phase-1 registers; phase 2 redistributes
// via double-buffered k-slice Hb (wave j's acc == H2 cols [j*32,+32) == phase-2 k-step j; R19 protocol).
// MODE 0: X(+Xh)->global. MODE 1: X tile into H1s (dead after phase 1); phase4 node GEMM1 -> global H1.
template<int MODE>
__global__ __launch_bounds__(512, 4) void k_mlp123(
    const _Float16* __restrict__ Tp,
    const _Float16* __restrict__ W1p, const float* __restrict__ b1,
    const _Float16* __restrict__ W2p, const float* __restrict__ b2,
    const _Float16* __restrict__ W3p, const float* __restrict__ b3,
    float* __restrict__ Xout, _Float16* __restrict__ Xhout,
    const _Float16* __restrict__ W1p3, const float* __restrict__ b13,
    _Float16* __restrict__ H1o,
    int st_gbase, const float* __restrict__ stsrc)
{
    __shared__ _Float16 A1h[64][LDP];      // 5.1 KB (T staging, phase 0 only)
    __shared__ _Float16 B1h[256][LDP];     // 20.5 KB (W1 / W2 / W3 / W1_3)
    __shared__ _Float16 H1s[64][LH2];      // 33.8 KB (H1 phases 0-1; X|st tile in MODE 1 phases 2-4)
    __shared__ _Float16 Hb[2][64][LDP];    // 10.2 KB (H2 k-slice double buffer)  -> 69.6 KB total

    int tid = threadIdx.x;
    int lane = tid & 63, wid = tid >> 6;
    int la = lane & 15, lg = lane >> 4;
    int r0 = blockIdx.x * 64;

    // ================= phase 0: H1s = relu(T @ W1^T + b1), 64x256, K=96
    {
        f32x4 acc0[4][2] = {};
        for (int k0 = 0; k0 < KP1; k0 += 32) {
            if (tid < 256) {
                int ar = tid >> 2, aq = (tid & 3) * 8;
                *(f16x8*)&A1h[ar][aq] = *(const f16x8*)&Tp[(size_t)(r0 + ar) * KP1 + k0 + aq];
            }
#pragma unroll
            for (int j = 0; j < 2; ++j) {
                int id = j * 512 + tid;
                int br = id >> 2, bq = (id & 3) * 8;
                *(f16x8*)&B1h[br][bq] = *(const f16x8*)&W1p[(size_t)br * KP1 + k0 + bq];
            }
            __syncthreads();

            int kf = lg * 8;
            f16x8 ah[4], bh[2];
#pragma unroll
            for (int m = 0; m < 4; ++m) ah[m] = *(const f16x8*)&A1h[m * 16 + la][kf];
#pragma unroll
            for (int n = 0; n < 2; ++n) bh[n] = *(const f16x8*)&B1h[wid * 32 + n * 16 + la][kf];
#pragma unroll
            for (int m = 0; m < 4; ++m)
#pragma unroll
                for (int n = 0; n < 2; ++n)
                    acc0[m][n] = __builtin_amdgcn_mfma_f32_16x16x32_f16(ah[m], bh[n], acc0[m][n], 0, 0, 0);
            __syncthreads();
        }
#pragma unroll
        for (int n = 0; n < 2; ++n) {
            int col = wid * 32 + n * 16 + la;
            float bv = b1[col];
#pragma unroll
            for (int m = 0; m < 4; ++m) {
                int row = m * 16 + lg * 4;
#pragma unroll
                for (int r = 0; r < 4; ++r) {
                    H1s[row + r][col] = (_Float16)fmaxf(acc0[m][n][r] + bv, 0.0f);
                }
            }
        }
        __syncthreads();
    }

    // ================= phase 1: H2(regs) = H1s @ W2^T; wave wid owns cols [wid*32,+32)
    f32x4 acc[4][2] = {};
    for (int k0 = 0; k0 < H; k0 += 32) {
#pragma unroll
        for (int j = 0; j < 2; ++j) {
            int id = j * 512 + tid;
            int br = id >> 2, bq = (id & 3) * 8;
            *(f16x8*)&B1h[br][bq] = *(const f16x8*)&W2p[(size_t)br * H + k0 + bq];
        }
        __syncthreads();

        int kf = lg * 8;
        f16x8 ah[4], bh[2];
#pragma unroll
        for (int m = 0; m < 4; ++m) ah[m] = *(const f16x8*)&H1s[m * 16 + la][k0 + kf];
#pragma unroll
        for (int n = 0; n < 2; ++n) bh[n] = *(const f16x8*)&B1h[wid * 32 + n * 16 + la][kf];
#pragma unroll
        for (int m = 0; m < 4; ++m)
#pragma unroll
            for (int n = 0; n < 2; ++n)
                acc[m][n] = __builtin_amdgcn_mfma_f32_16x16x32_f16(ah[m], bh[n], acc[m][n], 0, 0, 0);
        __syncthreads();
    }

    // ================= phase 2: Xtile = relu(H2+b2) @ W3^T + b3; H2 fed per-k-step by wave j via Hb
    int wm = wid >> 2, wn = wid & 3;
    f32x4 acc2[2] = {};
    for (int j = 0; j < 8; ++j) {
        int k0 = j * 32;
        if (tid < 256) {                   // W3 k-chunk: 64 rows x 4 chunks
            int br = tid >> 2, bq = (tid & 3) * 8;
            *(f16x8*)&B1h[br][bq] = *(const f16x8*)&W3p[(size_t)br * H + k0 + bq];
        }
        if (wid == j) {                    // dump this wave's H2 slice (bias+relu)
#pragma unroll
            for (int n = 0; n < 2; ++n) {
                int col = n * 16 + la;
                float bv = b2[k0 + col];
#pragma unroll
                for (int m = 0; m < 4; ++m) {
                    int row = m * 16 + lg * 4;
#pragma unroll
                    for (int r = 0; r < 4; ++r) {
                        Hb[j & 1][row + r][col] = (_Float16)fmaxf(acc[m][n][r] + bv, 0.0f);
                    }
                }
            }
        }
        __syncthreads();

        int kf = lg * 8;
        f16x8 ah[2], bh;
#pragma unroll
        for (int m = 0; m < 2; ++m) ah[m] = *(const f16x8*)&Hb[j & 1][wm * 32 + m * 16 + la][kf];
        bh = *(const f16x8*)&B1h[wn * 16 + la][kf];
#pragma unroll
        for (int m = 0; m < 2; ++m)
            acc2[m] = __builtin_amdgcn_mfma_f32_16x16x32_f16(ah[m], bh, acc2[m], 0, 0, 0);
        __syncthreads();
    }
    {
        int col = wn * 16 + la;
        float bv = b3[col];
#pragma unroll
        for (int m = 0; m < 2; ++m) {
            int rloc = wm * 32 + m * 16 + lg * 4;
#pragma unroll
            for (int r = 0; r < 4; ++r) {
                float v = fmaxf(acc2[m][r] + bv, 0.0f);
                if (MODE == 0) {
                    size_t o = (size_t)(r0 + rloc + r) * D + col;
                    Xout[o] = v;
                    Xhout[o] = (_Float16)v;
                } else {
                    H1s[rloc + r][col] = (_Float16)v;   // X tile into H1s (dead after phase 1)
                }
            }
        }
    }

    if (MODE == 1) {
        {   // static cols 64..79 + zero pad 80..95 into H1s
            int row = tid >> 3, c2 = (tid & 7) * 2;
            int g = st_gbase + r0 + row;
            float2 sv = *(const float2*)&stsrc[(size_t)g * S + c2];
            H1s[row][D + c2] = (_Float16)sv.x;
            H1s[row][D + c2 + 1] = (_Float16)sv.y;
            H1s[row][F + c2] = (_Float16)0.0f;
            H1s[row][F + c2 + 1] = (_Float16)0.0f;
        }
        __syncthreads();

        // phase 4: H1' = relu([X|st|0] @ W1_3^T + b1_3), 64x256, K=96
        f32x4 acc4[4][2] = {};
        for (int k0 = 0; k0 < KP1; k0 += 32) {
#pragma unroll
            for (int j = 0; j < 2; ++j) {
                int id = j * 512 + tid;
                int br = id >> 2, bq = (id & 3) * 8;
                *(f16x8*)&B1h[br][bq] = *(const f16x8*)&W1p3[(size_t)br * KP1 + k0 + bq];
            }
            __syncthreads();

            int kf = lg * 8;
            f16x8 ah[4], bh[2];
#pragma unroll
            for (int m = 0; m < 4; ++m) ah[m] = *(const f16x8*)&H1s[m * 16 + la][k0 + kf];
#pragma unroll
            for (int n = 0; n < 2; ++n) bh[n] = *(const f16x8*)&B1h[wid * 32 + n * 16 + la][kf];
#pragma unroll
            for (int m = 0; m < 4; ++m)
#pragma unroll
                for (int n = 0; n < 2; ++n)
                    acc4[m][n] = __builtin_amdgcn_mfma_f32_16x16x32_f16(ah[m], bh[n], acc4[m][n], 0, 0, 0);
            __syncthreads();
        }
#pragma unroll
        for (int n = 0; n < 2; ++n) {
            int col = wid * 32 + n * 16 + la;
            float bv = b13[col];
#pragma unroll
            for (int m = 0; m < 4; ++m) {
                int row = r0 + m * 16 + lg * 4;
#pragma unroll
                for (int r = 0; r < 4; ++r) {
                    H1o[(size_t)(row + r) * H + col] = (_Float16)fmaxf(acc4[m][n][r] + bv, 0.0f);
                }
            }
        }
    }
}

// ---------------------------------------------------------------- node_dnn GEMM2+GEMM3 (reads global H1) — writes X + Xh — R24-proven
__global__ __launch_bounds__(512, 4) void k_mlp23(
    const _Float16* __restrict__ H1p,
    const _Float16* __restrict__ W2p, const float* __restrict__ b2,
    const _Float16* __restrict__ W3p, const float* __restrict__ b3,
    float* __restrict__ Xout, _Float16* __restrict__ Xhout)
{
    __shared__ _Float16 A1h[64][LDP];
    __shared__ _Float16 B1h[256][LDP];
    __shared__ _Float16 H2hs[64][LH2];

    int tid = threadIdx.x;
    int lane = tid & 63, wid = tid >> 6;
    int la = lane & 15, lg = lane >> 4;
    int r0 = blockIdx.x * 64;

    // phase 1: H2 = relu(H1 @ W2^T + b2)
    f32x4 acc[4][2] = {};
    for (int k0 = 0; k0 < H; k0 += 32) {
        if (tid < 256) {
            int ar = tid >> 2, aq = (tid & 3) * 8;
            *(f16x8*)&A1h[ar][aq] = *(const f16x8*)&H1p[(size_t)(r0 + ar) * H + k0 + aq];
        }
#pragma unroll
        for (int j = 0; j < 2; ++j) {
            int id = j * 512 + tid;
            int br = id >> 2, bq = (id & 3) * 8;
            *(f16x8*)&B1h[br][bq] = *(const f16x8*)&W2p[(size_t)br * H + k0 + bq];
        }
        __syncthreads();

        int kf = lg * 8;
        f16x8 ah[4], bh[2];
#pragma unroll
        for (int m = 0; m < 4; ++m) ah[m] = *(const f16x8*)&A1h[m * 16 + la][kf];
#pragma unroll
        for (int n = 0; n < 2; ++n) bh[n] = *(const f16x8*)&B1h[wid * 32 + n * 16 + la][kf];
#pragma unroll
        for (int m = 0; m < 4; ++m)
#pragma unroll
            for (int n = 0; n < 2; ++n)
                acc[m][n] = __builtin_amdgcn_mfma_f32_16x16x32_f16(ah[m], bh[n], acc[m][n], 0, 0, 0);
        __syncthreads();
    }
#pragma unroll
    for (int n = 0; n < 2; ++n) {
        int col = wid * 32 + n * 16 + la;
        float bv = b2[col];
#pragma unroll
        for (int m = 0; m < 4; ++m) {
            int row = m * 16 + lg * 4;
#pragma unroll
            for (int r = 0; r < 4; ++r) {
                H2hs[row + r][col] = (_Float16)fmaxf(acc[m][n][r] + bv, 0.0f);
            }
        }
    }
    __syncthreads();

    // phase 2: X = relu(H2 @ W3^T + b3)
    int wm = wid >> 2, wn = wid & 3;
    f32x4 acc2[2] = {};
    for (int k0 = 0; k0 < H; k0 += 32) {
        if (tid < 256) {
            int br = tid >> 2, bq = (tid & 3) * 8;
            *(f16x8*)&B1h[br][bq] = *(const f16x8*)&W3p[(size_t)br * H + k0 + bq];
        }
        __syncthreads();

        int kf = lg * 8;
        f16x8 ah[2], bh;
#pragma unroll
        for (int m = 0; m < 2; ++m) ah[m] = *(const f16x8*)&H2hs[wm * 32 + m * 16 + la][k0 + kf];
        bh = *(const f16x8*)&B1h[wn * 16 + la][kf];
#pragma unroll
        for (int m = 0; m < 2; ++m)
            acc2[m] = __builtin_amdgcn_mfma_f32_16x16x32_f16(ah[m], bh, acc2[m], 0, 0, 0);
        __syncthreads();
    }
    {
        int col = wn * 16 + la;
        float bv = b3[col];
#pragma unroll
        for (int m = 0; m < 2; ++m) {
            int rloc = wm * 32 + m * 16 + lg * 4;
#pragma unroll
            for (int r = 0; r < 4; ++r) {
                float v = fmaxf(acc2[m][r] + bv, 0.0f);
                size_t o = (size_t)(r0 + rloc + r) * D + col;
                Xout[o] = v;
                Xhout[o] = (_Float16)v;
            }
        }
    }
}

// ---------------------------------------------------------------- two-stage pooling
#define PROWS 1024
__global__ __launch_bounds__(256) void k_pool2(const float* __restrict__ X,
                                               const int* __restrict__ bidx,
                                               float* __restrict__ PL) {
    __shared__ float lds[NG * D];
    int tid = threadIdx.x;
    for (int i = tid; i < NG * D; i += 256) lds[i] = 0.0f;
    __syncthreads();
    int base = blockIdx.x * PROWS;
    int f = tid & 63, rg = tid >> 6;
    for (int r = base + rg; r < base + PROWS; r += 4) {
        int g = bidx[r];
        atomicAdd(&lds[g * D + f], X[(size_t)r * D + f]);
    }
    __syncthreads();
    for (int i = tid; i < NG * D; i += 256) {
        float v = lds[i];
        if (v != 0.0f) fatomic_add(&PL[i], v);
    }
}

// ---------------------------------------------------------------- final linear head
__global__ void k_final(const float* __restrict__ pooled, const float* __restrict__ lin_w,
                        const float* __restrict__ lin_b, float* __restrict__ out) {
    int g = threadIdx.x;
    if (g >= NG) return;
    float acc = lin_b[0];
#pragma unroll
    for (int d2 = 0; d2 < D; ++d2) acc += pooled[g * D + d2] * lin_w[d2];
    out[g] = fmaxf(acc, 0.0f);
}

// ---------------------------------------------------------------- launch
extern "C" void kernel_launch(void* const* d_in, const int* in_sizes, int n_in,
                              void* d_out, int out_size, void* d_ws, size_t ws_size,
                              hipStream_t stream) {
    const float* x0    = (const float*)d_in[0];
    const float* stat  = (const float*)d_in[1];
    const float* W1    = (const float*)d_in[2];
    const float* b1    = (const float*)d_in[3];
    const float* W2    = (const float*)d_in[4];
    const float* b2    = (const float*)d_in[5];
    const float* W3    = (const float*)d_in[6];
    const float* b3    = (const float*)d_in[7];
    const float* eps   = (const float*)d_in[8];
    const float* lin_w = (const float*)d_in[9];
    const float* lin_b = (const float*)d_in[10];
    const int* inner_src = (const int*)d_in[11];
    const int* inner_dst = (const int*)d_in[12];
    const int* fwd_src   = (const int*)d_in[13];
    const int* fwd_dst   = (const int*)d_in[14];
    const int* bwd_src   = (const int*)d_in[15];
    const int* bwd_dst   = (const int*)d_in[16];
    const int* bidx      = (const int*)d_in[17];

    float* X  = (float*)d_ws;                                 // NND*64 f32
    float* PL = X + (size_t)NND * D;                          // NG*64 f32
    _Float16* Xh  = (_Float16*)(PL + NG * D);                 // [NND][64] fp16 mirror
    _Float16* st16 = Xh + (size_t)NND * D;                    // [NND][16] fp16 static
    _Float16* Th  = st16 + (size_t)NND * S;                   // [P][96]
    _Float16* H1p = Th + (size_t)P * KP1;                     // [P][256]
    _Float16* w1p = H1p + (size_t)P * H;                      // [4][256][96]
    _Float16* w2p = w1p + (size_t)4 * H * KP1;                // [4][256][256]
    _Float16* w3p = w2p + (size_t)4 * H * H;                  // [4][64][256]
    int* deg      = (int*)(w3p + (size_t)4 * D * H);          // NSETS*P
    int* rowstart = deg + (size_t)NSETS * P;                  // NSETS*RSP
    int* rank     = rowstart + (size_t)NSETS * RSP;           // NSETS*EDG
    int* elist    = rank + (size_t)NSETS * EDG;               // NSETS*EDG

    // ---- init X/Xh + zero deg/PL
    {
        int tot = NND * D + NSETS * P + NG * D;
        k_init_x<<<(tot + 255) / 256, 256, 0, stream>>>(x0, X, Xh, deg, PL);
    }
    // ---- weight prep (single fp16) + static fp16
    {
        int tot = 4 * H * KP1 + 4 * H * H + 4 * D * H + NND * S;
        k_wconv_all<<<(tot + 255) / 256, 256, 0, stream>>>(W1, W2, W3, stat, w1p, w2p, w3p, st16);
    }
    // ---- CSR build (R15-proven 3-kernel pipeline)
    k_csr_hist<<<(NSETS * EDG) / 256, 256, 0, stream>>>(inner_dst, fwd_dst, bwd_dst, deg, rank);
    k_csr_scan<<<NSETS, 1024, 0, stream>>>(deg, rowstart);
    k_csr_scatter<<<(NSETS * EDG) / 256, 256, 0, stream>>>(inner_src, inner_dst, fwd_src, fwd_dst,
                                                           bwd_src, bwd_dst, rowstart, rank, elist);

    _Float16* w13p = w1p + (size_t)3 * H * KP1;
    const float* b13 = b1 + 3 * H;

    auto conv_plain = [&](int set, int gbase_out) {
        k_mlp123<0><<<P / 64, 512, 0, stream>>>(
            Th,
            w1p + (size_t)set * H * KP1, b1 + set * H,
            w2p + (size_t)set * H * H, b2 + set * H,
            w3p + (size_t)set * D * H, b3 + set * D,
            X + (size_t)gbase_out * D, Xh + (size_t)gbase_out * D,
            nullptr, nullptr, nullptr, 0, nullptr);
    };
    auto conv_fused = [&](int set, int gbase_node) {
        k_mlp123<1><<<P / 64, 512, 0, stream>>>(
            Th,
            w1p + (size_t)set * H * KP1, b1 + set * H,
            w2p + (size_t)set * H * H, b2 + set * H,
            w3p + (size_t)set * D * H, b3 + set * D,
            nullptr, nullptr,
            w13p, b13, H1p, gbase_node, stat);
    };
    auto node_dnn = [&](int gbase_out) {
        k_mlp23<<<P / 64, 512, 0, stream>>>(
            H1p,
            w2p + (size_t)3 * H * H, b2 + 3 * H,
            w3p + (size_t)3 * D * H, b3 + 3 * D,
            X + (size_t)gbase_out * D, Xh + (size_t)gbase_out * D);
    };
    auto gather = [&](int t, int dst_gbase, int src_gbase, int ei) {
        k_gather_T<<<P / 4, 256, 0, stream>>>(
            X, Xh, st16, elist + (size_t)t * EDG, rowstart + (size_t)t * RSP,
            Th, dst_gbase, src_gbase, eps, ei, stat);
    };

    // forward pass
    for (int il = 0; il < NLAYERS; ++il) {
        int s0 = il * P;
        gather(il, s0, s0, 0);
        conv_plain(0, s0);
        if (il == NLAYERS - 1) continue;
        gather(5 + il, s0 + P, s0, 1);
        conv_fused(1, s0 + P);
        node_dnn(s0 + P);
    }
    // backward pass
    for (int il = NLAYERS - 1; il >= 1; --il) {
        int s0 = (il - 1) * P;
        gather(9 + (il - 1), s0, s0 + P, 2);
        conv_plain(2, s0);
        gather(il - 1, s0, s0, 0);
        conv_fused(0, s0);
        node_dnn(s0);
    }

    k_pool2<<<NND / PROWS, 256, 0, stream>>>(X, bidx, PL);
    k_final<<<1, 64, 0, stream>>>(PL, lin_w, lin_b, (float*)d_out);
}

// Round 28
// 909.640 us; speedup vs baseline: 1.0498x; 1.0498x over previous
//
#include <hip/hip_runtime.h>

#define P 16384
#define NLAYERS 5
#define NND 98304          // P*(NLAYERS+1)
#define D 64
#define S 16
#define F 80               // D+S
#define KP1 96             // K of layer-1 GEMM padded to 32
#define H 256
#define EDG 262144         // 1<<18
#define NG 64
#define NSETS 13           // 5 inner + 4 fwd + 4 bwd
#define RSP 16385          // rowstart pitch (P+1)
#define LDP 40             // LDS K-stride for 32-chunks (80B rows, <=2-way aliasing)
#define LH2 264            // H1s/H2s LDS row stride (256+8)
#define LXS 100            // X-tile LDS row stride (96+4)

typedef __attribute__((ext_vector_type(8))) _Float16 f16x8;
typedef __attribute__((ext_vector_type(4))) _Float16 f16x4;
typedef __attribute__((ext_vector_type(4))) float f32x4;

// ---------------------------------------------------------------- utilities
__device__ __forceinline__ void fatomic_add(float* p, float v) {
    unsafeAtomicAdd(p, v);
}

// ---------------------------------------------------------------- init X (+fp16 mirror) + zero deg + zero PL
__global__ void k_init_x(const float* __restrict__ x0, float* __restrict__ X,
                         _Float16* __restrict__ Xh,
                         int* __restrict__ deg, float* __restrict__ PL) {
    int idx = blockIdx.x * blockDim.x + threadIdx.x;
    if (idx < NND * D) {
        int row = idx >> 6, f = idx & 63;
        float v = (f == 0) ? x0[row] : 0.0f;
        X[idx] = v;
        Xh[idx] = (_Float16)v;
        return;
    }
    int r = idx - NND * D;
    if (r < NSETS * P) { deg[r] = 0; return; }
    r -= NSETS * P;
    if (r < NG * D) PL[r] = 0.0f;
}

// ---------------------------------------------------------------- weight transpose -> fp16 + static -> fp16
__global__ void k_wconv_all(const float* __restrict__ W1, const float* __restrict__ W2,
                            const float* __restrict__ W3, const float* __restrict__ stat,
                            _Float16* __restrict__ w1, _Float16* __restrict__ w2,
                            _Float16* __restrict__ w3, _Float16* __restrict__ st16) {
    const int n1 = 4 * H * KP1, n2 = 4 * H * H, n3 = 4 * D * H;
    int idx = blockIdx.x * blockDim.x + threadIdx.x;
    if (idx >= n1 + n2 + n3) {
        int i = idx - (n1 + n2 + n3);
        if (i < NND * S) st16[i] = (_Float16)stat[i];
        return;
    }
    const float* W; _Float16* h; int K, N, Kp, i;
    if (idx < n1)              { W = W1; h = w1; K = F; N = H; Kp = KP1; i = idx; }
    else if (idx < n1 + n2)    { W = W2; h = w2; K = H; N = H; Kp = H;   i = idx - n1; }
    else                       { W = W3; h = w3; K = H; N = D; Kp = H;  i = idx - n1 - n2; }
    int set = i / (N * Kp), rem = i - set * (N * Kp);
    int n = rem / Kp, kp = rem - n * Kp;
    float v = (kp < K) ? W[(size_t)set * K * N + (size_t)kp * N + n] : 0.0f;
    h[i] = (_Float16)v;
}

// ---------------------------------------------------------------- CSR build (batched, 13 sets) — R15-proven
__device__ __forceinline__ const int* set_ptr(int t, const int* inner, const int* fwd,
                                              const int* bwd) {
    if (t < 5) return inner + (size_t)t * EDG;
    if (t < 9) return fwd + (size_t)(t - 5) * EDG;
    return bwd + (size_t)(t - 9) * EDG;
}

__global__ void k_csr_hist(const int* __restrict__ inner_dst, const int* __restrict__ fwd_dst,
                           const int* __restrict__ bwd_dst, int* __restrict__ deg,
                           int* __restrict__ rank) {
    int idx = blockIdx.x * blockDim.x + threadIdx.x;
    if (idx >= NSETS * EDG) return;
    int t = idx >> 18, e = idx & (EDG - 1);
    const int* dstp = set_ptr(t, inner_dst, fwd_dst, bwd_dst);
    rank[idx] = atomicAdd(&deg[t * P + dstp[e]], 1);
}

__global__ __launch_bounds__(1024) void k_csr_scan(const int* __restrict__ deg,
                                                   int* __restrict__ rowstart) {
    __shared__ int part[1024];
    int t = blockIdx.x;
    const int* d = deg + t * P;
    int* rs = rowstart + (size_t)t * RSP;
    int tid = threadIdx.x;
    int base = tid * 16;
    int loc[16], sum = 0;
#pragma unroll
    for (int i = 0; i < 16; ++i) { loc[i] = sum; sum += d[base + i]; }
    part[tid] = sum;
    __syncthreads();
    for (int off = 1; off < 1024; off <<= 1) {
        int v = (tid >= off) ? part[tid - off] : 0;
        __syncthreads();
        part[tid] += v;
        __syncthreads();
    }
    int pre = tid ? part[tid - 1] : 0;
#pragma unroll
    for (int i = 0; i < 16; ++i) rs[base + i] = pre + loc[i];
    if (tid == 1023) rs[P] = pre + sum;
}

__global__ void k_csr_scatter(const int* __restrict__ inner_src, const int* __restrict__ inner_dst,
                              const int* __restrict__ fwd_src, const int* __restrict__ fwd_dst,
                              const int* __restrict__ bwd_src, const int* __restrict__ bwd_dst,
                              const int* __restrict__ rowstart, const int* __restrict__ rank,
                              int* __restrict__ elist) {
    int idx = blockIdx.x * blockDim.x + threadIdx.x;
    if (idx >= NSETS * EDG) return;
    int t = idx >> 18, e = idx & (EDG - 1);
    const int* srcp = set_ptr(t, inner_src, fwd_src, bwd_src);
    const int* dstp = set_ptr(t, inner_dst, fwd_dst, bwd_dst);
    int dv = dstp[e];
    elist[(size_t)t * EDG + rowstart[(size_t)t * RSP + dv] + rank[idx]] = srcp[e];
}

// ---------------------------------------------------------------- gather conv input (wave per node, 4-row ILP, fp16 reads)
__global__ __launch_bounds__(256) void k_gather_T(const float* __restrict__ X,
                                                  const _Float16* __restrict__ Xh,
                                                  const _Float16* __restrict__ st16,
                                                  const int* __restrict__ elist,
                                                  const int* __restrict__ rowstart,
                                                  _Float16* __restrict__ Th,
                                                  int dst_gbase, int src_gbase,
                                                  const float* __restrict__ eps, int ei,
                                                  const float* __restrict__ stf) {
    int wv = threadIdx.x >> 6, l = threadIdx.x & 63;
    int v = blockIdx.x * 4 + wv;
    int beg = rowstart[v], end = rowstart[v + 1];
    float scale = 1.0f + eps[ei];
    int rg = l >> 4, c = l & 15;
    float ax0 = 0.f, ax1 = 0.f, ax2 = 0.f, ax3 = 0.f, as = 0.f;
    int i = beg;
    for (; i + 4 <= end; i += 4) {
        int s = src_gbase + elist[i + rg];
        f16x4 xv = *(const f16x4*)&Xh[(size_t)s * D + 4 * c];
        ax0 += (float)xv[0]; ax1 += (float)xv[1]; ax2 += (float)xv[2]; ax3 += (float)xv[3];
        as += (float)st16[(size_t)s * S + c];
    }
    if (i < end) {
        int rem = end - i;
        if (rg < rem) {
            int s = src_gbase + elist[i + rg];
            f16x4 xv = *(const f16x4*)&Xh[(size_t)s * D + 4 * c];
            ax0 += (float)xv[0]; ax1 += (float)xv[1]; ax2 += (float)xv[2]; ax3 += (float)xv[3];
            as += (float)st16[(size_t)s * S + c];
        }
    }
#pragma unroll
    for (int off = 16; off < 64; off <<= 1) {
        ax0 += __shfl_xor(ax0, off, 64);
        ax1 += __shfl_xor(ax1, off, 64);
        ax2 += __shfl_xor(ax2, off, 64);
        ax3 += __shfl_xor(ax3, off, 64);
        as  += __shfl_xor(as,  off, 64);
    }
    if (l < 16) {
        int g = dst_gbase + v;
        float4 sx = *(const float4*)&X[(size_t)g * D + 4 * l];
        f16x4 hv;
        hv[0] = (_Float16)(ax0 + scale * sx.x);
        hv[1] = (_Float16)(ax1 + scale * sx.y);
        hv[2] = (_Float16)(ax2 + scale * sx.z);
        hv[3] = (_Float16)(ax3 + scale * sx.w);
        *(f16x4*)&Th[(size_t)v * KP1 + 4 * l] = hv;
        Th[(size_t)v * KP1 + D + l] = (_Float16)(as + scale * stf[(size_t)g * S + l]);
        Th[(size_t)v * KP1 + F + l] = (_Float16)0.0f;   // pad cols 80..95
    }
}

// ---------------------------------------------------------------- fused conv MLP: T -> H1(LDS) -> H2(LDS) -> X
// 64-row tile, 8 waves, 1 block/CU. MODE 0: X(+Xh)->global. MODE 1: X in LDS; phase4 node GEMM1 -> global H1.
template<int MODE>
__global__ __launch_bounds__(512, 2) void k_mlp123(
    const _Float16* __restrict__ Tp,
    const _Float16* __restrict__ W1p, const float* __restrict__ b1,
    const _Float16* __restrict__ W2p, const float* __restrict__ b2,
    const _Float16* __restrict__ W3p, const float* __restrict__ b3,
    float* __restrict__ Xout, _Float16* __restrict__ Xhout,
    const _Float16* __restrict__ W1p3, const float* __restrict__ b13,
    _Float16* __restrict__ H1o,
    int st_gbase, const float* __restrict__ stsrc)
{
    __shared__ _Float16 A1h[64][LDP];                  // 5.1 KB (T k-chunk staging)
    __shared__ _Float16 B1h[256][LDP];                 // 20.5 KB (W1 / W2 / W3 / W1_3)
    __shared__ _Float16 H1s[64][LH2];                  // 33.8 KB
    __shared__ _Float16 H2hs[64][LH2];                 // 33.8 KB
    __shared__ _Float16 Xsh[(MODE == 1) ? 64 : 1][LXS];// 12.8 KB (MODE 1)

    int tid = threadIdx.x;
    int lane = tid & 63, wid = tid >> 6;
    int la = lane & 15, lg = lane >> 4;
    int r0 = blockIdx.x * 64;

    // ================= phase 0: H1s = relu(T @ W1^T + b1), 64x256, K=96
    {
        f32x4 acc0[4][2] = {};
        for (int k0 = 0; k0 < KP1; k0 += 32) {
            if (tid < 256) {
                int ar = tid >> 2, aq = (tid & 3) * 8;
                *(f16x8*)&A1h[ar][aq] = *(const f16x8*)&Tp[(size_t)(r0 + ar) * KP1 + k0 + aq];
            }
#pragma unroll
            for (int j = 0; j < 2; ++j) {
                int id = j * 512 + tid;
                int br = id >> 2, bq = (id & 3) * 8;
                *(f16x8*)&B1h[br][bq] = *(const f16x8*)&W1p[(size_t)br * KP1 + k0 + bq];
            }
            __syncthreads();

            int kf = lg * 8;
            f16x8 ah[4], bh[2];
#pragma unroll
            for (int m = 0; m < 4; ++m) ah[m] = *(const f16x8*)&A1h[m * 16 + la][kf];
#pragma unroll
            for (int n = 0; n < 2; ++n) bh[n] = *(const f16x8*)&B1h[wid * 32 + n * 16 + la][kf];
#pragma unroll
            for (int m = 0; m < 4; ++m)
#pragma unroll
                for (int n = 0; n < 2; ++n)
                    acc0[m][n] = __builtin_amdgcn_mfma_f32_16x16x32_f16(ah[m], bh[n], acc0[m][n], 0, 0, 0);
            __syncthreads();
        }
#pragma unroll
        for (int n = 0; n < 2; ++n) {
            int col = wid * 32 + n * 16 + la;
            float bv = b1[col];
#pragma unroll
            for (int m = 0; m < 4; ++m) {
                int row = m * 16 + lg * 4;
#pragma unroll
                for (int r = 0; r < 4; ++r) {
                    H1s[row + r][col] = (_Float16)fmaxf(acc0[m][n][r] + bv, 0.0f);
                }
            }
        }
        __syncthreads();
    }

    // ================= phase 1: H2 = relu(H1s @ W2^T + b2), 64x256, K=256
    f32x4 acc[4][2] = {};
    for (int k0 = 0; k0 < H; k0 += 32) {
#pragma unroll
        for (int j = 0; j < 2; ++j) {
            int id = j * 512 + tid;
            int br = id >> 2, bq = (id & 3) * 8;
            *(f16x8*)&B1h[br][bq] = *(const f16x8*)&W2p[(size_t)br * H + k0 + bq];
        }
        __syncthreads();

        int kf = lg * 8;
        f16x8 ah[4], bh[2];
#pragma unroll
        for (int m = 0; m < 4; ++m) ah[m] = *(const f16x8*)&H1s[m * 16 + la][k0 + kf];
#pragma unroll
        for (int n = 0; n < 2; ++n) bh[n] = *(const f16x8*)&B1h[wid * 32 + n * 16 + la][kf];
#pragma unroll
        for (int m = 0; m < 4; ++m)
#pragma unroll
            for (int n = 0; n < 2; ++n)
                acc[m][n] = __builtin_amdgcn_mfma_f32_16x16x32_f16(ah[m], bh[n], acc[m][n], 0, 0, 0);
        __syncthreads();
    }
#pragma unroll
    for (int n = 0; n < 2; ++n) {
        int col = wid * 32 + n * 16 + la;
        float bv = b2[col];
#pragma unroll
        for (int m = 0; m < 4; ++m) {
            int row = m * 16 + lg * 4;
#pragma unroll
            for (int r = 0; r < 4; ++r) {
                H2hs[row + r][col] = (_Float16)fmaxf(acc[m][n][r] + bv, 0.0f);
            }
        }
    }
    __syncthreads();

    // ================= phase 2: Xtile = relu(H2 @ W3^T + b3), K=256
    int wm = wid >> 2, wn = wid & 3;
    f32x4 acc2[2] = {};
    {
        for (int k0 = 0; k0 < H; k0 += 32) {
            if (tid < 256) {
                int br = tid >> 2, bq = (tid & 3) * 8;
                *(f16x8*)&B1h[br][bq] = *(const f16x8*)&W3p[(size_t)br * H + k0 + bq];
            }
            __syncthreads();

            int kf = lg * 8;
            f16x8 ah[2], bh;
#pragma unroll
            for (int m = 0; m < 2; ++m) ah[m] = *(const f16x8*)&H2hs[wm * 32 + m * 16 + la][k0 + kf];
            bh = *(const f16x8*)&B1h[wn * 16 + la][kf];
#pragma unroll
            for (int m = 0; m < 2; ++m)
                acc2[m] = __builtin_amdgcn_mfma_f32_16x16x32_f16(ah[m], bh, acc2[m], 0, 0, 0);
            __syncthreads();
        }
    }
    {
        int col = wn * 16 + la;
        float bv = b3[col];
#pragma unroll
        for (int m = 0; m < 2; ++m) {
            int rloc = wm * 32 + m * 16 + lg * 4;
#pragma unroll
            for (int r = 0; r < 4; ++r) {
                float v = fmaxf(acc2[m][r] + bv, 0.0f);
                if (MODE == 0) {
                    size_t o = (size_t)(r0 + rloc + r) * D + col;
                    Xout[o] = v;
                    Xhout[o] = (_Float16)v;
                } else {
                    Xsh[rloc + r][col] = (_Float16)v;
                }
            }
        }
    }

    if (MODE == 1) {
        {   // static cols 64..79 + zero pad 80..95
            int row = tid >> 3, c2 = (tid & 7) * 2;
            int g = st_gbase + r0 + row;
            float2 sv = *(const float2*)&stsrc[(size_t)g * S + c2];
            Xsh[row][D + c2] = (_Float16)sv.x;
            Xsh[row][D + c2 + 1] = (_Float16)sv.y;
            Xsh[row][F + c2] = (_Float16)0.0f;
            Xsh[row][F + c2 + 1] = (_Float16)0.0f;
        }
        __syncthreads();

        // phase 4: H1' = relu([X|st|0] @ W1_3^T + b1_3), 64x256, K=96
        f32x4 acc4[4][2] = {};
        for (int k0 = 0; k0 < KP1; k0 += 32) {
#pragma unroll
            for (int j = 0; j < 2; ++j) {
                int id = j * 512 + tid;
                int br = id >> 2, bq = (id & 3) * 8;
                *(f16x8*)&B1h[br][bq] = *(const f16x8*)&W1p3[(size_t)br * KP1 + k0 + bq];
            }
            __syncthreads();

            int kf = lg * 8;
            f16x8 ah[4], bh[2];
#pragma unroll
            for (int m = 0; m < 4; ++m) ah[m] = *(const f16x8*)&Xsh[m * 16 + la][k0 + kf];
#pragma unroll
            for (int n = 0; n < 2; ++n) bh[n] = *(const f16x8*)&B1h[wid * 32 + n * 16 + la][kf];
#pragma unroll
            for (int m = 0; m < 4; ++m)
#pragma unroll
                for (int n = 0; n < 2; ++n)
                    acc4[m][n] = __builtin_amdgcn_mfma_f32_16x16x32_f16(ah[m], bh[n], acc4[m][n], 0, 0, 0);
            __syncthreads();
        }
#pragma unroll
        for (int n = 0; n < 2; ++n) {
            int col = wid * 32 + n * 16 + la;
            float bv = b13[col];
#pragma unroll
            for (int m = 0; m < 4; ++m) {
                int row = r0 + m * 16 + lg * 4;
#pragma unroll
                for (int r = 0; r < 4; ++r) {
                    H1o[(size_t)(row + r) * H + col] = (_Float16)fmaxf(acc4[m][n][r] + bv, 0.0f);
                }
            }
        }
    }
}

// ---------------------------------------------------------------- node_dnn GEMM2+GEMM3 (reads global H1) — writes X + Xh
__global__ __launch_bounds__(512, 4) void k_mlp23(
    const _Float16* __restrict__ H1p,
    const _Float16* __restrict__ W2p, const float* __restrict__ b2,
    const _Float16* __restrict__ W3p, const float* __restrict__ b3,
    float* __restrict__ Xout, _Float16* __restrict__ Xhout)
{
    __shared__ _Float16 A1h[64][LDP];
    __shared__ _Float16 B1h[256][LDP];
    __shared__ _Float16 H2hs[64][LH2];

    int tid = threadIdx.x;
    int lane = tid & 63, wid = tid >> 6;
    int la = lane & 15, lg = lane >> 4;
    int r0 = blockIdx.x * 64;

    // phase 1: H2 = relu(H1 @ W2^T + b2)
    f32x4 acc[4][2] = {};
    for (int k0 = 0; k0 < H; k0 += 32) {
        if (tid < 256) {
            int ar = tid >> 2, aq = (tid & 3) * 8;
            *(f16x8*)&A1h[ar][aq] = *(const f16x8*)&H1p[(size_t)(r0 + ar) * H + k0 + aq];
        }
#pragma unroll
        for (int j = 0; j < 2; ++j) {
            int id = j * 512 + tid;
            int br = id >> 2, bq = (id & 3) * 8;
            *(f16x8*)&B1h[br][bq] = *(const f16x8*)&W2p[(size_t)br * H + k0 + bq];
        }
        __syncthreads();

        int kf = lg * 8;
        f16x8 ah[4], bh[2];
#pragma unroll
        for (int m = 0; m < 4; ++m) ah[m] = *(const f16x8*)&A1h[m * 16 + la][kf];
#pragma unroll
        for (int n = 0; n < 2; ++n) bh[n] = *(const f16x8*)&B1h[wid * 32 + n * 16 + la][kf];
#pragma unroll
        for (int m = 0; m < 4; ++m)
#pragma unroll
            for (int n = 0; n < 2; ++n)
                acc[m][n] = __builtin_amdgcn_mfma_f32_16x16x32_f16(ah[m], bh[n], acc[m][n], 0, 0, 0);
        __syncthreads();
    }
#pragma unroll
    for (int n = 0; n < 2; ++n) {
        int col = wid * 32 + n * 16 + la;
        float bv = b2[col];
#pragma unroll
        for (int m = 0; m < 4; ++m) {
            int row = m * 16 + lg * 4;
#pragma unroll
            for (int r = 0; r < 4; ++r) {
                H2hs[row + r][col] = (_Float16)fmaxf(acc[m][n][r] + bv, 0.0f);
            }
        }
    }
    __syncthreads();

    // phase 2: X = relu(H2 @ W3^T + b3)
    int wm = wid >> 2, wn = wid & 3;
    f32x4 acc2[2] = {};
    for (int k0 = 0; k0 < H; k0 += 32) {
        if (tid < 256) {
            int br = tid >> 2, bq = (tid & 3) * 8;
            *(f16x8*)&B1h[br][bq] = *(const f16x8*)&W3p[(size_t)br * H + k0 + bq];
        }
        __syncthreads();

        int kf = lg * 8;
        f16x8 ah[2], bh;
#pragma unroll
        for (int m = 0; m < 2; ++m) ah[m] = *(const f16x8*)&H2hs[wm * 32 + m * 16 + la][k0 + kf];
        bh = *(const f16x8*)&B1h[wn * 16 + la][kf];
#pragma unroll
        for (int m = 0; m < 2; ++m)
            acc2[m] = __builtin_amdgcn_mfma_f32_16x16x32_f16(ah[m], bh, acc2[m], 0, 0, 0);
        __syncthreads();
    }
    {
        int col = wn * 16 + la;
        float bv = b3[col];
#pragma unroll
        for (int m = 0; m < 2; ++m) {
            int rloc = wm * 32 + m * 16 + lg * 4;
#pragma unroll
            for (int r = 0; r < 4; ++r) {
                float v = fmaxf(acc2[m][r] + bv, 0.0f);
                size_t o = (size_t)(r0 + rloc + r) * D + col;
                Xout[o] = v;
                Xhout[o] = (_Float16)v;
            }
        }
    }
}

// ---------------------------------------------------------------- two-stage pooling
#define PROWS 1024
__global__ __launch_bounds__(256) void k_pool2(const float* __restrict__ X,
                                               const int* __restrict__ bidx,
                                               float* __restrict__ PL) {
    __shared__ float lds[NG * D];
    int tid = threadIdx.x;
    for (int i = tid; i < NG * D; i += 256) lds[i] = 0.0f;
    __syncthreads();
    int base = blockIdx.x * PROWS;
    int f = tid & 63, rg = tid >> 6;
    for (int r = base + rg; r < base + PROWS; r += 4) {
        int g = bidx[r];
        atomicAdd(&lds[g * D + f], X[(size_t)r * D + f]);
    }
    __syncthreads();
    for (int i = tid; i < NG * D; i += 256) {
        float v = lds[i];
        if (v != 0.0f) fatomic_add(&PL[i], v);
    }
}

// ---------------------------------------------------------------- final linear head
__global__ void k_final(const float* __restrict__ pooled, const float* __restrict__ lin_w,
                        const float* __restrict__ lin_b, float* __restrict__ out) {
    int g = threadIdx.x;
    if (g >= NG) return;
    float acc = lin_b[0];
#pragma unroll
    for (int d2 = 0; d2 < D; ++d2) acc += pooled[g * D + d2] * lin_w[d2];
    out[g] = fmaxf(acc, 0.0f);
}

// ---------------------------------------------------------------- launch
extern "C" void kernel_launch(void* const* d_in, const int* in_sizes, int n_in,
                              void* d_out, int out_size, void* d_ws, size_t ws_size,
                              hipStream_t stream) {
    const float* x0    = (const float*)d_in[0];
    const float* stat  = (const float*)d_in[1];
    const float* W1    = (const float*)d_in[2];
    const float* b1    = (const float*)d_in[3];
    const float* W2    = (const float*)d_in[4];
    const float* b2    = (const float*)d_in[5];
    const float* W3    = (const float*)d_in[6];
    const float* b3    = (const float*)d_in[7];
    const float* eps   = (const float*)d_in[8];
    const float* lin_w = (const float*)d_in[9];
    const float* lin_b = (const float*)d_in[10];
    const int* inner_src = (const int*)d_in[11];
    const int* inner_dst = (const int*)d_in[12];
    const int* fwd_src   = (const int*)d_in[13];
    const int* fwd_dst   = (const int*)d_in[14];
    const int* bwd_src   = (const int*)d_in[15];
    const int* bwd_dst   = (const int*)d_in[16];
    const int* bidx      = (const int*)d_in[17];

    float* X  = (float*)d_ws;                                 // NND*64 f32
    float* PL = X + (size_t)NND * D;                          // NG*64 f32
    _Float16* Xh  = (_Float16*)(PL + NG * D);                 // [NND][64] fp16 mirror
    _Float16* st16 = Xh + (size_t)NND * D;                    // [NND][16] fp16 static
    _Float16* Th  = st16 + (size_t)NND * S;                   // [P][96]
    _Float16* H1p = Th + (size_t)P * KP1;                     // [P][256]
    _Float16* w1p = H1p + (size_t)P * H;                      // [4][256][96]
    _Float16* w2p = w1p + (size_t)4 * H * KP1;                // [4][256][256]
    _Float16* w3p = w2p + (size_t)4 * H * H;                  // [4][64][256]
    int* deg      = (int*)(w3p + (size_t)4 * D * H);          // NSETS*P
    int* rowstart = deg + (size_t)NSETS * P;                  // NSETS*RSP
    int* rank     = rowstart + (size_t)NSETS * RSP;           // NSETS*EDG
    int* elist    = rank + (size_t)NSETS * EDG;               // NSETS*EDG

    // ---- init X/Xh + zero deg/PL
    {
        int tot = NND * D + NSETS * P + NG * D;
        k_init_x<<<(tot + 255) / 256, 256, 0, stream>>>(x0, X, Xh, deg, PL);
    }
    // ---- weight prep (single fp16) + static fp16
    {
        int tot = 4 * H * KP1 + 4 * H * H + 4 * D * H + NND * S;
        k_wconv_all<<<(tot + 255) / 256, 256, 0, stream>>>(W1, W2, W3, stat, w1p, w2p, w3p, st16);
    }
    // ---- CSR build (R15-proven 3-kernel pipeline)
    k_csr_hist<<<(NSETS * EDG) / 256, 256, 0, stream>>>(inner_dst, fwd_dst, bwd_dst, deg, rank);
    k_csr_scan<<<NSETS, 1024, 0, stream>>>(deg, rowstart);
    k_csr_scatter<<<(NSETS * EDG) / 256, 256, 0, stream>>>(inner_src, inner_dst, fwd_src, fwd_dst,
                                                           bwd_src, bwd_dst, rowstart, rank, elist);

    _Float16* w13p = w1p + (size_t)3 * H * KP1;
    const float* b13 = b1 + 3 * H;

    auto conv_plain = [&](int set, int gbase_out) {
        k_mlp123<0><<<P / 64, 512, 0, stream>>>(
            Th,
            w1p + (size_t)set * H * KP1, b1 + set * H,
            w2p + (size_t)set * H * H, b2 + set * H,
            w3p + (size_t)set * D * H, b3 + set * D,
            X + (size_t)gbase_out * D, Xh + (size_t)gbase_out * D,
            nullptr, nullptr, nullptr, 0, nullptr);
    };
    auto conv_fused = [&](int set, int gbase_node) {
        k_mlp123<1><<<P / 64, 512, 0, stream>>>(
            Th,
            w1p + (size_t)set * H * KP1, b1 + set * H,
            w2p + (size_t)set * H * H, b2 + set * H,
            w3p + (size_t)set * D * H, b3 + set * D,
            nullptr, nullptr,
            w13p, b13, H1p, gbase_node, stat);
    };
    auto node_dnn = [&](int gbase_out) {
        k_mlp23<<<P / 64, 512, 0, stream>>>(
            H1p,
            w2p + (size_t)3 * H * H, b2 + 3 * H,
            w3p + (size_t)3 * D * H, b3 + 3 * D,
            X + (size_t)gbase_out * D, Xh + (size_t)gbase_out * D);
    };
    auto gather = [&](int t, int dst_gbase, int src_gbase, int ei) {
        k_gather_T<<<P / 4, 256, 0, stream>>>(
            X, Xh, st16, elist + (size_t)t * EDG, rowstart + (size_t)t * RSP,
            Th, dst_gbase, src_gbase, eps, ei, stat);
    };

    // forward pass
    for (int il = 0; il < NLAYERS; ++il) {
        int s0 = il * P;
        gather(il, s0, s0, 0);
        conv_plain(0, s0);
        if (il == NLAYERS - 1) continue;
        gather(5 + il, s0 + P, s0, 1);
        conv_fused(1, s0 + P);
        node_dnn(s0 + P);
    }
    // backward pass
    for (int il = NLAYERS - 1; il >= 1; --il) {
        int s0 = (il - 1) * P;
        gather(9 + (il - 1), s0, s0 + P, 2);
        conv_plain(2, s0);
        gather(il - 1, s0, s0, 0);
        conv_fused(0, s0);
        node_dnn(s0);
    }

    k_pool2<<<NND / PROWS, 256, 0, stream>>>(X, bidx, PL);
    k_final<<<1, 64, 0, stream>>>(PL, lin_w, lin_b, (float*)d_out);
}